// Round 1
// baseline (538.861 us; speedup 1.0000x reference)
//
#include <hip/hip_runtime.h>
#include <hip/hip_fp16.h>

typedef _Float16 half8 __attribute__((ext_vector_type(8)));
typedef float f32x4 __attribute__((ext_vector_type(4)));

#define BATCH 65536
#define M1 196608   // 3*BATCH
#define K1 160      // 157 padded
#define N1 512      // 256 phi1 | 256 phi2
#define K2 256
#define N2 480      // 471 padded
#define K3 480
#define N3 256

// ---------------- prep: transpose+convert weights to fp16 ----------------
// W1t[512][160]  (n-major, k contiguous), W2t[2][480][256], R1t[2][256][480]
__global__ void prep_kernel(const float* __restrict__ w1a, const float* __restrict__ w1b,
                            const float* __restrict__ w2a, const float* __restrict__ w2b,
                            const float* __restrict__ r1a, const float* __restrict__ r1b,
                            _Float16* __restrict__ W1t, _Float16* __restrict__ W2t,
                            _Float16* __restrict__ R1t) {
    int e = blockIdx.x * 256 + threadIdx.x;
    if (e < 512 * 160) {
        int n = e / 160, k = e % 160;
        float v = 0.f;
        if (k < 157) v = (n < 256) ? w1a[k * 256 + n] : w1b[k * 256 + (n - 256)];
        W1t[e] = (_Float16)v;
        return;
    }
    e -= 512 * 160;
    if (e < 2 * 480 * 256) {
        int net = e / (480 * 256), r = e % (480 * 256);
        int n = r / 256, k = r % 256;
        const float* w = net ? w2b : w2a;
        float v = (n < 471) ? w[k * 471 + n] : 0.f;
        W2t[net * 480 * 256 + n * 256 + k] = (_Float16)v;
        return;
    }
    e -= 2 * 480 * 256;
    if (e < 2 * 256 * 480) {
        int net = e / (256 * 480), r = e % (256 * 480);
        int n = r / 480, k = r % 480;
        const float* w = net ? r1b : r1a;
        float v = (k < 471) ? w[k * 256 + n] : 0.f;
        R1t[net * 256 * 480 + n * 480 + k] = (_Float16)v;
    }
}

// ---------------- build X (3B x 160) fp16, padded ----------------
__global__ void build_x(const float* __restrict__ obs, const float* __restrict__ act,
                        const float* __restrict__ nodes, _Float16* __restrict__ Xh) {
    int e = blockIdx.x * 256 + threadIdx.x;   // < 196608*160 = 31,457,280
    int k = e % K1;
    int r = e / K1;            // r = o*BATCH + b
    int o = r >> 16, b = r & 65535;
    float v;
    if (k < 4)        v = act[b * 4 + k];
    else if (k < 14)  v = obs[b * 55 + (k - 4)];
    else if (k < 29)  v = obs[b * 55 + 10 + o * 15 + (k - 14)];
    else if (k < 157) v = nodes[(long)r * 128 + (k - 29)];
    else              v = 0.f;
    Xh[e] = (_Float16)v;
}

// ---------------- GEMM1: H = relu(X @ W1cat + b1cat), M=3B,N=512,K=160 ----------------
// BM=128 BN=128, full-K staged, 4 waves, wave tile 64x64
__global__ __launch_bounds__(256) void gemm1(const _Float16* __restrict__ Xh,
                                             const _Float16* __restrict__ W1t,
                                             const float* __restrict__ b1a,
                                             const float* __restrict__ b1b,
                                             _Float16* __restrict__ H) {
    __shared__ _Float16 As[128 * 168];
    __shared__ _Float16 Bs[128 * 168];
    const int tid = threadIdx.x;
    const int m0 = blockIdx.x * 128, n0 = blockIdx.y * 128;
#pragma unroll
    for (int i = 0; i < 10; ++i) {
        int c = tid + i * 256, row = c / 20, col = c % 20;
        half8 v = *(const half8*)(Xh + (long)(m0 + row) * K1 + col * 8);
        *(half8*)(As + row * 168 + col * 8) = v;
    }
#pragma unroll
    for (int i = 0; i < 10; ++i) {
        int c = tid + i * 256, row = c / 20, col = c % 20;
        half8 v = *(const half8*)(W1t + (n0 + row) * K1 + col * 8);
        *(half8*)(Bs + row * 168 + col * 8) = v;
    }
    __syncthreads();
    const int wid = tid >> 6, lane = tid & 63;
    const int wr = (wid >> 1) * 64, wc = (wid & 1) * 64;
    const int lm = lane & 15, lk = (lane >> 4) * 8;
    f32x4 acc[4][4] = {};
#pragma unroll
    for (int ks = 0; ks < 5; ++ks) {
        half8 a[4], bb[4];
#pragma unroll
        for (int i = 0; i < 4; ++i) a[i] = *(const half8*)(As + (wr + i * 16 + lm) * 168 + ks * 32 + lk);
#pragma unroll
        for (int j = 0; j < 4; ++j) bb[j] = *(const half8*)(Bs + (wc + j * 16 + lm) * 168 + ks * 32 + lk);
#pragma unroll
        for (int i = 0; i < 4; ++i)
#pragma unroll
            for (int j = 0; j < 4; ++j)
                acc[i][j] = __builtin_amdgcn_mfma_f32_16x16x32_f16(a[i], bb[j], acc[i][j], 0, 0, 0);
    }
#pragma unroll
    for (int j = 0; j < 4; ++j) {
        int n = n0 + wc + j * 16 + lm;
        float bias = (n < 256) ? b1a[n] : b1b[n - 256];
#pragma unroll
        for (int i = 0; i < 4; ++i) {
            int mrow = m0 + wr + i * 16 + (lane >> 4) * 4;
#pragma unroll
            for (int rg = 0; rg < 4; ++rg) {
                float v = acc[i][j][rg] + bias;
                v = v > 0.f ? v : 0.f;
                H[(long)(mrow + rg) * N1 + n] = (_Float16)v;
            }
        }
    }
}

// ---------------- GEMM2: OutSum = sum_o relu(H_o @ W2 + b2), per net ----------------
// M=B (BM=128), N=480 (BN=160), K=256 (BK=64), 4 waves, wave tile 64x80
__global__ __launch_bounds__(256) void gemm2(const _Float16* __restrict__ H,
                                             const _Float16* __restrict__ W2t,
                                             const float* __restrict__ b2a,
                                             const float* __restrict__ b2b,
                                             _Float16* __restrict__ OutSum) {
    __shared__ _Float16 As[128 * 72];
    __shared__ _Float16 Bs[160 * 72];
    const int tid = threadIdx.x;
    const int b0 = blockIdx.x * 128, n0 = blockIdx.y * 160, net = blockIdx.z;
    const _Float16* W = W2t + net * 480 * 256;
    const float* bias_p = net ? b2b : b2a;
    const int wid = tid >> 6, lane = tid & 63;
    const int wr = (wid >> 1) * 64, wc = (wid & 1) * 80;
    const int lm = lane & 15, lk = (lane >> 4) * 8;
    float bias[5];
#pragma unroll
    for (int j = 0; j < 5; ++j) {
        int n = n0 + wc + j * 16 + lm;
        bias[j] = (n < 471) ? bias_p[n] : 0.f;
    }
    f32x4 sum[4][5] = {};
    for (int o = 0; o < 3; ++o) {
        f32x4 acc[4][5] = {};
        for (int kc = 0; kc < 4; ++kc) {
            __syncthreads();
#pragma unroll
            for (int i = 0; i < 4; ++i) {
                int c = tid + i * 256, row = c >> 3, col = c & 7;
                half8 v = *(const half8*)(H + (long)(o * BATCH + b0 + row) * N1 + net * 256 + kc * 64 + col * 8);
                *(half8*)(As + row * 72 + col * 8) = v;
            }
#pragma unroll
            for (int i = 0; i < 5; ++i) {
                int c = tid + i * 256, row = c >> 3, col = c & 7;
                half8 v = *(const half8*)(W + (n0 + row) * 256 + kc * 64 + col * 8);
                *(half8*)(Bs + row * 72 + col * 8) = v;
            }
            __syncthreads();
#pragma unroll
            for (int ks = 0; ks < 2; ++ks) {
                half8 a[4], bb[5];
#pragma unroll
                for (int i = 0; i < 4; ++i) a[i] = *(const half8*)(As + (wr + i * 16 + lm) * 72 + ks * 32 + lk);
#pragma unroll
                for (int j = 0; j < 5; ++j) bb[j] = *(const half8*)(Bs + (wc + j * 16 + lm) * 72 + ks * 32 + lk);
#pragma unroll
                for (int i = 0; i < 4; ++i)
#pragma unroll
                    for (int j = 0; j < 5; ++j)
                        acc[i][j] = __builtin_amdgcn_mfma_f32_16x16x32_f16(a[i], bb[j], acc[i][j], 0, 0, 0);
            }
        }
#pragma unroll
        for (int i = 0; i < 4; ++i)
#pragma unroll
            for (int j = 0; j < 5; ++j)
#pragma unroll
                for (int rg = 0; rg < 4; ++rg) {
                    float v = acc[i][j][rg] + bias[j];
                    sum[i][j][rg] += (v > 0.f ? v : 0.f);
                }
    }
#pragma unroll
    for (int j = 0; j < 5; ++j) {
        int n = n0 + wc + j * 16 + lm;
#pragma unroll
        for (int i = 0; i < 4; ++i) {
            int mrow = b0 + wr + i * 16 + (lane >> 4) * 4;
#pragma unroll
            for (int rg = 0; rg < 4; ++rg)
                OutSum[(long)net * BATCH * N2 + (long)(mrow + rg) * N2 + n] = (_Float16)sum[i][j][rg];
        }
    }
}

// ---------------- GEMM3: Hr = relu(OutSum @ R1 + rb1), per net ----------------
// M=B (BM=128), N=256 (BN=128), K=480 (BK=96), 4 waves, 64x64
__global__ __launch_bounds__(256) void gemm3(const _Float16* __restrict__ OutSum,
                                             const _Float16* __restrict__ R1t,
                                             const float* __restrict__ rb1a,
                                             const float* __restrict__ rb1b,
                                             _Float16* __restrict__ Hr) {
    __shared__ _Float16 As[128 * 104];
    __shared__ _Float16 Bs[128 * 104];
    const int tid = threadIdx.x;
    const int b0 = blockIdx.x * 128, n0 = blockIdx.y * 128, net = blockIdx.z;
    const _Float16* A = OutSum + (long)net * BATCH * N2;
    const _Float16* Wn = R1t + net * 256 * 480;
    const float* bias_p = net ? rb1b : rb1a;
    const int wid = tid >> 6, lane = tid & 63;
    const int wr = (wid >> 1) * 64, wc = (wid & 1) * 64;
    const int lm = lane & 15, lk = (lane >> 4) * 8;
    f32x4 acc[4][4] = {};
    for (int kc = 0; kc < 5; ++kc) {
        __syncthreads();
#pragma unroll
        for (int i = 0; i < 6; ++i) {
            int c = tid + i * 256, row = c / 12, col = c % 12;
            half8 v = *(const half8*)(A + (long)(b0 + row) * K3 + kc * 96 + col * 8);
            *(half8*)(As + row * 104 + col * 8) = v;
        }
#pragma unroll
        for (int i = 0; i < 6; ++i) {
            int c = tid + i * 256, row = c / 12, col = c % 12;
            half8 v = *(const half8*)(Wn + (n0 + row) * K3 + kc * 96 + col * 8);
            *(half8*)(Bs + row * 104 + col * 8) = v;
        }
        __syncthreads();
#pragma unroll
        for (int ks = 0; ks < 3; ++ks) {
            half8 a[4], bb[4];
#pragma unroll
            for (int i = 0; i < 4; ++i) a[i] = *(const half8*)(As + (wr + i * 16 + lm) * 104 + ks * 32 + lk);
#pragma unroll
            for (int j = 0; j < 4; ++j) bb[j] = *(const half8*)(Bs + (wc + j * 16 + lm) * 104 + ks * 32 + lk);
#pragma unroll
            for (int i = 0; i < 4; ++i)
#pragma unroll
                for (int j = 0; j < 4; ++j)
                    acc[i][j] = __builtin_amdgcn_mfma_f32_16x16x32_f16(a[i], bb[j], acc[i][j], 0, 0, 0);
        }
    }
#pragma unroll
    for (int j = 0; j < 4; ++j) {
        int n = n0 + wc + j * 16 + lm;
        float bias = bias_p[n];
#pragma unroll
        for (int i = 0; i < 4; ++i) {
            int mrow = b0 + wr + i * 16 + (lane >> 4) * 4;
#pragma unroll
            for (int rg = 0; rg < 4; ++rg) {
                float v = acc[i][j][rg] + bias;
                v = v > 0.f ? v : 0.f;
                Hr[(long)net * BATCH * N3 + (long)(mrow + rg) * N3 + n] = (_Float16)v;
            }
        }
    }
}

// ---------------- qdot: q = Hr . rho_w2 + rho_b2 ----------------
__global__ void qdot(const _Float16* __restrict__ Hr,
                     const float* __restrict__ r2a, const float* __restrict__ r2b,
                     const float* __restrict__ rb2a, const float* __restrict__ rb2b,
                     float* __restrict__ out) {
    int idx = blockIdx.x * 256 + threadIdx.x;  // < 131072
    int net = idx >> 16, b = idx & 65535;
    const _Float16* row = Hr + (long)net * BATCH * N3 + (long)b * N3;
    const float* w = net ? r2b : r2a;
    float s = net ? rb2b[0] : rb2a[0];
#pragma unroll 4
    for (int i = 0; i < 256; i += 8) {
        half8 v = *(const half8*)(row + i);
#pragma unroll
        for (int j = 0; j < 8; ++j) s += (float)v[j] * w[i + j];
    }
    out[idx] = s;
}

extern "C" void kernel_launch(void* const* d_in, const int* in_sizes, int n_in,
                              void* d_out, int out_size, void* d_ws, size_t ws_size,
                              hipStream_t stream) {
    const float* obs  = (const float*)d_in[0];
    const float* act  = (const float*)d_in[1];
    const float* nodes= (const float*)d_in[2];
    const float* p1w1 = (const float*)d_in[3];  const float* p1b1 = (const float*)d_in[4];
    const float* p1w2 = (const float*)d_in[5];  const float* p1b2 = (const float*)d_in[6];
    const float* p2w1 = (const float*)d_in[7];  const float* p2b1 = (const float*)d_in[8];
    const float* p2w2 = (const float*)d_in[9];  const float* p2b2 = (const float*)d_in[10];
    const float* r1w1 = (const float*)d_in[11]; const float* r1b1 = (const float*)d_in[12];
    const float* r1w2 = (const float*)d_in[13]; const float* r1b2 = (const float*)d_in[14];
    const float* r2w1 = (const float*)d_in[15]; const float* r2b1 = (const float*)d_in[16];
    const float* r2w2 = (const float*)d_in[17]; const float* r2b2 = (const float*)d_in[18];

    // workspace layout (bytes, all 16B aligned)
    const size_t oW1t = 0;                       // 512*160*2      = 163,840
    const size_t oW2t = 163840;                  // 2*480*256*2    = 491,520
    const size_t oR1t = 655360;                  // 2*256*480*2    = 491,520
    const size_t oXh  = 1146880;                 // 196608*160*2   = 62,914,560
    const size_t oH   = 64061440;                // 196608*512*2   = 201,326,592 (Hr aliases this later)
    const size_t oOut = 265388032;               // 2*65536*480*2  = 125,829,120
    const size_t need = 391217152;
    if (ws_size < need) return;   // fail cleanly rather than corrupt

    char* ws = (char*)d_ws;
    _Float16* W1t = (_Float16*)(ws + oW1t);
    _Float16* W2t = (_Float16*)(ws + oW2t);
    _Float16* R1t = (_Float16*)(ws + oR1t);
    _Float16* Xh  = (_Float16*)(ws + oXh);
    _Float16* H   = (_Float16*)(ws + oH);
    _Float16* Hr  = (_Float16*)(ws + oH);   // alias: H dead after gemm2
    _Float16* Osum= (_Float16*)(ws + oOut);
    float* out = (float*)d_out;

    prep_kernel<<<2240, 256, 0, stream>>>(p1w1, p2w1, p1w2, p2w2, r1w1, r2w1, W1t, W2t, R1t);
    build_x<<<122880, 256, 0, stream>>>(obs, act, nodes, Xh);
    gemm1<<<dim3(M1 / 128, N1 / 128, 1), 256, 0, stream>>>(Xh, W1t, p1b1, p2b1, H);
    gemm2<<<dim3(BATCH / 128, N2 / 160, 2), 256, 0, stream>>>(H, W2t, p1b2, p2b2, Osum);
    gemm3<<<dim3(BATCH / 128, N3 / 128, 2), 256, 0, stream>>>(Osum, R1t, r1b1, r2b1, Hr);
    qdot<<<512, 256, 0, stream>>>(Hr, r1w2, r2w2, r1b2, r2b2, out);
}

// Round 2
// 416.670 us; speedup vs baseline: 1.2933x; 1.2933x over previous
//
#include <hip/hip_runtime.h>
#include <hip/hip_fp16.h>

typedef _Float16 half8 __attribute__((ext_vector_type(8)));
typedef _Float16 half4 __attribute__((ext_vector_type(4)));
typedef float f32x4 __attribute__((ext_vector_type(4)));

#define BATCH 65536
#define M1 196608   // 3*BATCH
#define K1 192      // 157 padded to 6*32
#define N1 512      // 256 phi1 | 256 phi2
#define K2 256
#define N2 512      // 471 padded to 512
#define K3 512
#define N3 256

// global -> LDS direct, 16B per lane, dest = wave-uniform base + lane*16
#define GLL16(g, l) __builtin_amdgcn_global_load_lds( \
    (const __attribute__((address_space(1))) unsigned int*)(const void*)(g), \
    (__attribute__((address_space(3))) unsigned int*)(void*)(l), 16, 0, 0)

// ---------------- prep: weights -> fp16 n-major k-contig, merged biases ----------------
__global__ void prep_kernel(const float* __restrict__ p1w1, const float* __restrict__ p2w1,
                            const float* __restrict__ p1w2, const float* __restrict__ p2w2,
                            const float* __restrict__ r1w1, const float* __restrict__ r2w1,
                            const float* __restrict__ p1b1, const float* __restrict__ p2b1,
                            const float* __restrict__ p1b2, const float* __restrict__ p2b2,
                            const float* __restrict__ rb1a, const float* __restrict__ rb1b,
                            _Float16* __restrict__ W1t, _Float16* __restrict__ W2t,
                            _Float16* __restrict__ R1t, float* __restrict__ b1cat,
                            float* __restrict__ b2cat, float* __restrict__ rbias) {
    int e = blockIdx.x * 256 + threadIdx.x;
    if (e < 98304) {  // W1t[512][192]
        int n = e / 192, k = e % 192;
        float v = 0.f;
        if (k < 157) v = (n < 256) ? p1w1[k * 256 + n] : p2w1[k * 256 + (n - 256)];
        W1t[e] = (_Float16)v;
        return;
    }
    e -= 98304;
    if (e < 262144) {  // W2t[2][512][256]
        int net = e >> 17, rr = e & 131071;
        int n = rr >> 8;
        int k = rr & 255;
        const float* w = net ? p2w2 : p1w2;
        W2t[(size_t)net * 131072 + rr] = (n < 471) ? (_Float16)w[k * 471 + n] : (_Float16)0.f;
        return;
    }
    e -= 262144;
    if (e < 262144) {  // R1t[2][256][512]
        int net = e >> 17, rr = e & 131071;
        int n = rr >> 9;
        int k = rr & 511;
        const float* w = net ? r2w1 : r1w1;
        R1t[(size_t)net * 131072 + rr] = (k < 471) ? (_Float16)w[k * 256 + n] : (_Float16)0.f;
        return;
    }
    e -= 262144;
    if (e < 512) { b1cat[e] = (e < 256) ? p1b1[e] : p2b1[e - 256]; return; }
    e -= 512;
    if (e < 1024) {
        int net = e >> 9, n = e & 511;
        b2cat[e] = (n < 471) ? (net ? p2b2 : p1b2)[n] : 0.f;
        return;
    }
    e -= 1024;
    if (e < 512) {
        int net = e >> 8, n = e & 255;
        rbias[e] = (net ? rb1b : rb1a)[n];
    }
}

// ---------------- build X (3B x 192) fp16, zero-padded ----------------
__global__ void build_x(const float* __restrict__ obs, const float* __restrict__ act,
                        const float* __restrict__ nodes, _Float16* __restrict__ Xh) {
    long e = ((long)blockIdx.x * 256 + threadIdx.x) * 4;   // < 196608*192
    int k0 = (int)(e % K1);
    long r = e / K1;
    int o = (int)(r >> 16), b = (int)(r & 65535);
    half4 v;
#pragma unroll
    for (int j = 0; j < 4; ++j) {
        int k = k0 + j;
        float f;
        if (k < 4)        f = act[b * 4 + k];
        else if (k < 14)  f = obs[b * 55 + (k - 4)];
        else if (k < 29)  f = obs[b * 55 + 10 + o * 15 + (k - 14)];
        else if (k < 157) f = nodes[r * 128 + (k - 29)];
        else              f = 0.f;
        v[j] = (_Float16)f;
    }
    *(half4*)(Xh + e) = v;
}

// ---------------- std GEMM: out = relu(A @ B^T + bias), fp16 out ----------------
// BM=BN=128, BK=32, 4 waves, wave tile 64x64, double-buffered global_load_lds
template<int RR>
__global__ __launch_bounds__(256) void gemm_std(
    const _Float16* __restrict__ A, int lda, long aZ,
    const _Float16* __restrict__ Bw, int ldb, long bZ,
    const float* __restrict__ bias, int biasZ,
    _Float16* __restrict__ out, int ldo, long oZ)
{
    __shared__ _Float16 As[2][4096];
    __shared__ _Float16 Bs[2][4096];
    const int tid = threadIdx.x;
    const int z = blockIdx.z;
    const int m0 = blockIdx.x * 128, n0 = blockIdx.y * 128;
    const _Float16* Ab = A + aZ * z + (long)m0 * lda;
    const _Float16* Bb = Bw + bZ * z + (long)n0 * ldb;
    const float* bp = bias + (long)biasZ * z;
    _Float16* op = out + oZ * z;
    const int wid = tid >> 6, lane = tid & 63;
    const int srow = tid >> 2, scolh = (tid & 3) << 3;  // staging: row 0..63, col-halves

    // stage round 0 into buf 0
    {
        const _Float16* sA = Ab + (long)srow * lda + scolh;
        const _Float16* sB = Bb + (long)srow * ldb + scolh;
        GLL16(sA, &As[0][0] + wid * 512);
        GLL16(sA + (long)64 * lda, &As[0][0] + 2048 + wid * 512);
        GLL16(sB, &Bs[0][0] + wid * 512);
        GLL16(sB + (long)64 * ldb, &Bs[0][0] + 2048 + wid * 512);
    }
    __syncthreads();

    const int wr = (wid >> 1) * 64, wc = (wid & 1) * 64;
    const int lm = lane & 15, lq = lane >> 4;
    f32x4 acc[4][4] = {};
    int cur = 0;
    for (int r = 0; r < RR; ++r) {
        if (r + 1 < RR) {  // prefetch next tile into other buffer (stays in flight over compute)
            int ko = (r + 1) * 32;
            const _Float16* sA = Ab + (long)srow * lda + ko + scolh;
            const _Float16* sB = Bb + (long)srow * ldb + ko + scolh;
            _Float16* dA = &As[cur ^ 1][0];
            _Float16* dB = &Bs[cur ^ 1][0];
            GLL16(sA, dA + wid * 512);
            GLL16(sA + (long)64 * lda, dA + 2048 + wid * 512);
            GLL16(sB, dB + wid * 512);
            GLL16(sB + (long)64 * ldb, dB + 2048 + wid * 512);
        }
        const _Float16* ab = &As[cur][0];
        const _Float16* bb = &Bs[cur][0];
        half8 a[4], b[4];
#pragma unroll
        for (int i = 0; i < 4; ++i) a[i] = *(const half8*)(ab + (wr + i * 16 + lm) * 32 + lq * 8);
#pragma unroll
        for (int j = 0; j < 4; ++j) b[j] = *(const half8*)(bb + (wc + j * 16 + lm) * 32 + lq * 8);
#pragma unroll
        for (int i = 0; i < 4; ++i)
#pragma unroll
            for (int j = 0; j < 4; ++j)
                acc[i][j] = __builtin_amdgcn_mfma_f32_16x16x32_f16(a[i], b[j], acc[i][j], 0, 0, 0);
        __syncthreads();
        cur ^= 1;
    }
#pragma unroll
    for (int j = 0; j < 4; ++j) {
        int n = n0 + wc + j * 16 + lm;
        float bi = bp[n];
#pragma unroll
        for (int i = 0; i < 4; ++i) {
            int mrow = m0 + wr + i * 16 + lq * 4;
#pragma unroll
            for (int rg = 0; rg < 4; ++rg) {
                float v = acc[i][j][rg] + bi;
                v = v > 0.f ? v : 0.f;
                op[(long)(mrow + rg) * ldo + n] = (_Float16)v;
            }
        }
    }
}

// ---------------- gemm2: OutSum = sum_o relu(H_o @ W2^T + b2), per net ----------------
// BM=128, BN=128, BK=32, 8 waves, wave tile 64x32, 24 rounds (3 obj x 8 kc)
__global__ __launch_bounds__(512) void gemm_sum(
    const _Float16* __restrict__ H, const _Float16* __restrict__ W2t,
    const float* __restrict__ b2cat, _Float16* __restrict__ OutSum)
{
    __shared__ _Float16 As[2][4096];
    __shared__ _Float16 Bs[2][4096];
    const int tid = threadIdx.x;
    const int net = blockIdx.z;
    const int b0 = blockIdx.x * 128, n0 = blockIdx.y * 128;
    const _Float16* Ab = H + (long)b0 * N1 + net * 256;
    const _Float16* Bb = W2t + (long)net * 131072 + (long)n0 * 256;
    const float* bp = b2cat + net * 512;
    const int wid = tid >> 6, lane = tid & 63;
    const int srow = tid >> 2, scolh = (tid & 3) << 3;  // row 0..127

    {
        const _Float16* sA = Ab + (long)srow * N1 + scolh;
        const _Float16* sB = Bb + (long)srow * 256 + scolh;
        GLL16(sA, &As[0][0] + wid * 512);
        GLL16(sB, &Bs[0][0] + wid * 512);
    }
    __syncthreads();

    const int wr = (wid >> 2) * 64, wc = (wid & 3) * 32;
    const int lm = lane & 15, lq = lane >> 4;
    float bi[2];
#pragma unroll
    for (int j = 0; j < 2; ++j) bi[j] = bp[n0 + wc + j * 16 + lm];
    f32x4 acc[2][2] = {{}};
    f32x4 acc2[2][2] = {{}};
    f32x4 sum[4][2] = {};
    // use two named halves to keep all indexing compile-time (i in 0..3 split as acc/acc2)
    f32x4 accA[4][2] = {};
    int cur = 0;
    for (int r = 0; r < 24; ++r) {
        if (r < 23) {
            int rn = r + 1;
            int obj = rn >> 3, ko = (rn & 7) * 32;
            const _Float16* sA = Ab + ((long)obj * BATCH + srow) * N1 + ko + scolh;
            const _Float16* sB = Bb + (long)srow * 256 + ko + scolh;
            _Float16* dA = &As[cur ^ 1][0];
            _Float16* dB = &Bs[cur ^ 1][0];
            GLL16(sA, dA + wid * 512);
            GLL16(sB, dB + wid * 512);
        }
        const _Float16* ab = &As[cur][0];
        const _Float16* bb = &Bs[cur][0];
        half8 a[4], b[2];
#pragma unroll
        for (int i = 0; i < 4; ++i) a[i] = *(const half8*)(ab + (wr + i * 16 + lm) * 32 + lq * 8);
#pragma unroll
        for (int j = 0; j < 2; ++j) b[j] = *(const half8*)(bb + (wc + j * 16 + lm) * 32 + lq * 8);
#pragma unroll
        for (int i = 0; i < 4; ++i)
#pragma unroll
            for (int j = 0; j < 2; ++j)
                accA[i][j] = __builtin_amdgcn_mfma_f32_16x16x32_f16(a[i], b[j], accA[i][j], 0, 0, 0);
        if ((r & 7) == 7) {  // object boundary: relu + accumulate, reset
#pragma unroll
            for (int i = 0; i < 4; ++i)
#pragma unroll
                for (int j = 0; j < 2; ++j) {
#pragma unroll
                    for (int rg = 0; rg < 4; ++rg) {
                        float v = accA[i][j][rg] + bi[j];
                        sum[i][j][rg] += (v > 0.f ? v : 0.f);
                    }
                    accA[i][j] = f32x4{0.f, 0.f, 0.f, 0.f};
                }
        }
        __syncthreads();
        cur ^= 1;
    }
    (void)acc; (void)acc2;
    _Float16* op = OutSum + (long)net * BATCH * N2;
#pragma unroll
    for (int j = 0; j < 2; ++j) {
        int n = n0 + wc + j * 16 + lm;
#pragma unroll
        for (int i = 0; i < 4; ++i) {
            int mrow = b0 + wr + i * 16 + lq * 4;
#pragma unroll
            for (int rg = 0; rg < 4; ++rg)
                op[(long)(mrow + rg) * N2 + n] = (_Float16)sum[i][j][rg];
        }
    }
}

// ---------------- qdot: q = Hr . rho_w2 + rho_b2 ----------------
__global__ void qdot(const _Float16* __restrict__ Hr,
                     const float* __restrict__ r2a, const float* __restrict__ r2b,
                     const float* __restrict__ rb2a, const float* __restrict__ rb2b,
                     float* __restrict__ out) {
    int idx = blockIdx.x * 256 + threadIdx.x;  // < 131072
    int net = idx >> 16, b = idx & 65535;
    const _Float16* row = Hr + (long)net * BATCH * N3 + (long)b * N3;
    const float* w = net ? r2b : r2a;
    float s = net ? rb2b[0] : rb2a[0];
#pragma unroll 4
    for (int i = 0; i < 256; i += 8) {
        half8 v = *(const half8*)(row + i);
#pragma unroll
        for (int j = 0; j < 8; ++j) s += (float)v[j] * w[i + j];
    }
    out[idx] = s;
}

extern "C" void kernel_launch(void* const* d_in, const int* in_sizes, int n_in,
                              void* d_out, int out_size, void* d_ws, size_t ws_size,
                              hipStream_t stream) {
    const float* obs  = (const float*)d_in[0];
    const float* act  = (const float*)d_in[1];
    const float* nodes= (const float*)d_in[2];
    const float* p1w1 = (const float*)d_in[3];  const float* p1b1 = (const float*)d_in[4];
    const float* p1w2 = (const float*)d_in[5];  const float* p1b2 = (const float*)d_in[6];
    const float* p2w1 = (const float*)d_in[7];  const float* p2b1 = (const float*)d_in[8];
    const float* p2w2 = (const float*)d_in[9];  const float* p2b2 = (const float*)d_in[10];
    const float* r1w1 = (const float*)d_in[11]; const float* r1b1 = (const float*)d_in[12];
    const float* r1w2 = (const float*)d_in[13]; const float* r1b2 = (const float*)d_in[14];
    const float* r2w1 = (const float*)d_in[15]; const float* r2b1 = (const float*)d_in[16];
    const float* r2w2 = (const float*)d_in[17]; const float* r2b2 = (const float*)d_in[18];

    // workspace layout (bytes, 16B aligned)
    const size_t oW1t  = 0;           // 512*192*2        = 196,608
    const size_t oW2t  = 196608;      // 2*512*256*2      = 524,288
    const size_t oR1t  = 720896;      // 2*256*512*2      = 524,288
    const size_t oB1   = 1245184;     // 512*4            = 2,048
    const size_t oB2   = 1247232;     // 2*512*4          = 4,096
    const size_t oRB   = 1251328;     // 2*256*4          = 2,048
    const size_t oXO   = 1253376;     // max(Xh 75,497,472 ; OutSum 134,217,728) — aliased in time
    const size_t oH    = 135471104;   // H 201,326,592 (Hr aliases after gemm2)
    const size_t need  = 336797696;
    if (ws_size < need) return;

    char* ws = (char*)d_ws;
    _Float16* W1t  = (_Float16*)(ws + oW1t);
    _Float16* W2t  = (_Float16*)(ws + oW2t);
    _Float16* R1t  = (_Float16*)(ws + oR1t);
    float*    b1cat= (float*)(ws + oB1);
    float*    b2cat= (float*)(ws + oB2);
    float*    rbias= (float*)(ws + oRB);
    _Float16* Xh   = (_Float16*)(ws + oXO);
    _Float16* Osum = (_Float16*)(ws + oXO);  // alias: Xh dead after gemm1
    _Float16* H    = (_Float16*)(ws + oH);
    _Float16* Hr   = (_Float16*)(ws + oH);   // alias: H dead after gemm2
    float* out = (float*)d_out;

    prep_kernel<<<2440, 256, 0, stream>>>(p1w1, p2w1, p1w2, p2w2, r1w1, r2w1,
                                          p1b1, p2b1, p1b2, p2b2, r1b1, r2b1,
                                          W1t, W2t, R1t, b1cat, b2cat, rbias);
    build_x<<<36864, 256, 0, stream>>>(obs, act, nodes, Xh);
    // gemm1: H = relu(X @ W1cat), M=3B, N=512, K=192
    gemm_std<6><<<dim3(M1 / 128, N1 / 128, 1), 256, 0, stream>>>(
        Xh, K1, 0L, W1t, K1, 0L, b1cat, 0, H, N1, 0L);
    // gemm2: OutSum = sum_o relu(H_o @ W2), M=B, N=512, K=3*256
    gemm_sum<<<dim3(BATCH / 128, N2 / 128, 2), 512, 0, stream>>>(H, W2t, b2cat, Osum);
    // gemm3: Hr = relu(OutSum @ R1), M=B, N=256, K=512, per net
    gemm_std<16><<<dim3(BATCH / 128, N3 / 128, 2), 256, 0, stream>>>(
        Osum, K3, (long)BATCH * K3, R1t, K3, (long)256 * K3, rbias, 256, Hr, N3, (long)BATCH * N3);
    qdot<<<512, 256, 0, stream>>>(Hr, r1w2, r2w2, r1b2, r2b2, out);
}

// Round 3
// 330.766 us; speedup vs baseline: 1.6291x; 1.2597x over previous
//
#include <hip/hip_runtime.h>
#include <hip/hip_fp16.h>

typedef _Float16 half8 __attribute__((ext_vector_type(8)));
typedef float f32x4 __attribute__((ext_vector_type(4)));

#define BATCH 65536
#define M1 196608   // 3*BATCH
#define K1 192      // 157 padded to 3*64, columns permuted: [nodes(128) | act(4) | body(10) | obj(15) | pad(35)]

// global -> LDS direct, 16B per lane, dest = wave-uniform base + lane*16
#define GLL16(g, l) __builtin_amdgcn_global_load_lds( \
    (const __attribute__((address_space(1))) unsigned int*)(const void*)(g), \
    (__attribute__((address_space(3))) unsigned int*)(void*)(l), 16, 0, 0)

// ---------------- prep: weights -> fp16 n-major k-contig (permuted/padded), merged biases ----------------
__global__ void prep_kernel(const float* __restrict__ p1w1, const float* __restrict__ p2w1,
                            const float* __restrict__ p1w2, const float* __restrict__ p2w2,
                            const float* __restrict__ r1w1, const float* __restrict__ r2w1,
                            const float* __restrict__ p1b1, const float* __restrict__ p2b1,
                            const float* __restrict__ p1b2, const float* __restrict__ p2b2,
                            const float* __restrict__ rb1a, const float* __restrict__ rb1b,
                            _Float16* __restrict__ W1t, _Float16* __restrict__ W2t,
                            _Float16* __restrict__ R1t, float* __restrict__ b1cat,
                            float* __restrict__ b2cat, float* __restrict__ rbias) {
    int e = blockIdx.x * 256 + threadIdx.x;
    if (e < 98304) {  // W1t[512][192]; col c<128 -> orig k=29+c (nodes), else orig k=c-128 (act/body/obj, same order)
        int n = e / 192, c = e % 192;
        int k = (c < 128) ? (29 + c) : (c - 128);
        float v = 0.f;
        if (c < 128 || (c - 128) < 29) v = (n < 256) ? p1w1[k * 256 + n] : p2w1[k * 256 + (n - 256)];
        W1t[e] = (_Float16)v;
        return;
    }
    e -= 98304;
    if (e < 262144) {  // W2t[2][512][256]
        int net = e >> 17, rr = e & 131071;
        int n = rr >> 8, k = rr & 255;
        const float* w = net ? p2w2 : p1w2;
        W2t[(size_t)net * 131072 + rr] = (n < 471) ? (_Float16)w[k * 471 + n] : (_Float16)0.f;
        return;
    }
    e -= 262144;
    if (e < 262144) {  // R1t[2][256][512]
        int net = e >> 17, rr = e & 131071;
        int n = rr >> 9, k = rr & 511;
        const float* w = net ? r2w1 : r1w1;
        R1t[(size_t)net * 131072 + rr] = (k < 471) ? (_Float16)w[k * 256 + n] : (_Float16)0.f;
        return;
    }
    e -= 262144;
    if (e < 512) { b1cat[e] = (e < 256) ? p1b1[e] : p2b1[e - 256]; return; }
    e -= 512;
    if (e < 1024) {
        int net = e >> 9, n = e & 511;
        b2cat[e] = (n < 471) ? (net ? p2b2 : p1b2)[n] : 0.f;
        return;
    }
    e -= 1024;
    if (e < 512) {
        int net = e >> 8, n = e & 255;
        rbias[e] = (net ? rb1b : rb1a)[n];
    }
}

// ---------------- build X (3B x 192) fp16, permuted cols: [nodes|act|body|obj|pad] ----------------
__global__ void build_x(const float* __restrict__ obs, const float* __restrict__ act,
                        const float* __restrict__ nodes, _Float16* __restrict__ Xh) {
    long idx = (long)blockIdx.x * 256 + threadIdx.x;   // one 16B chunk each; 196608*24 total
    int ch = (int)(idx % 24);
    long r = idx / 24;
    int o = (int)(r >> 16), b = (int)(r & 65535);
    half8 v;
    if (ch < 16) {                     // nodes, clean copy
        const float* s = nodes + r * 128 + ch * 8;
#pragma unroll
        for (int j = 0; j < 8; ++j) v[j] = (_Float16)s[j];
    } else if (ch < 20) {              // act/body/obj mixed region (cols 128..159)
#pragma unroll
        for (int j = 0; j < 8; ++j) {
            int lc = ch * 8 + j - 128;
            float f = 0.f;
            if (lc < 4)       f = act[b * 4 + lc];
            else if (lc < 14) f = obs[b * 55 + (lc - 4)];
            else if (lc < 29) f = obs[b * 55 + 10 + o * 15 + (lc - 14)];
            v[j] = (_Float16)f;
        }
    } else {                           // pad
#pragma unroll
        for (int j = 0; j < 8; ++j) v[j] = (_Float16)0.f;
    }
    *(half8*)(Xh + r * 192 + ch * 8) = v;
}

// ---------------- gemm1: H[net][3B][256] = relu(X @ W1cat + b1cat) ----------------
// BM=BN=128, BK=64, 8 waves (64x32 wave tiles), dbuf global_load_lds, XOR-swizzled LDS
__global__ __launch_bounds__(512) void gemm1(const _Float16* __restrict__ Xh,
                                             const _Float16* __restrict__ W1t,
                                             const float* __restrict__ b1cat,
                                             _Float16* __restrict__ H) {
    __shared__ _Float16 As[2][8192];
    __shared__ _Float16 Bs[2][8192];
    const int tid = threadIdx.x;
    // XCD swizzle + y-fast grouping: 6144 blocks = 8 XCD x 768; 4 y-blocks sharing an A panel are consecutive
    int bid = blockIdx.x;
    int w = (bid & 7) * 768 + (bid >> 3);
    const int m0 = (w >> 2) * 128, n0 = (w & 3) * 128;
    const _Float16* Ab = Xh + (long)m0 * K1;
    const _Float16* Bb = W1t + (long)n0 * K1;
    const int wid = tid >> 6, lane = tid & 63;
    const int lm = lane & 15, lq = lane >> 4;
    const int wr = (wid >> 2) * 64, wc = (wid & 3) * 32;
    const int xv = lm & 7;

#pragma unroll
    for (int t = 0; t < 2; ++t) {   // stage round 0
        int c = t * 512 + tid, row = c >> 3, q = (c & 7) ^ (row & 7);
        GLL16(Ab + (long)row * K1 + q * 8, &As[0][0] + t * 4096 + wid * 512);
        GLL16(Bb + (long)row * K1 + q * 8, &Bs[0][0] + t * 4096 + wid * 512);
    }
    __syncthreads();

    f32x4 acc[4][2] = {};
    int cur = 0;
    for (int r = 0; r < 3; ++r) {
        if (r < 2) {
            int ko = (r + 1) * 64;
            _Float16* dA = &As[cur ^ 1][0];
            _Float16* dB = &Bs[cur ^ 1][0];
#pragma unroll
            for (int t = 0; t < 2; ++t) {
                int c = t * 512 + tid, row = c >> 3, q = (c & 7) ^ (row & 7);
                GLL16(Ab + (long)row * K1 + ko + q * 8, dA + t * 4096 + wid * 512);
                GLL16(Bb + (long)row * K1 + ko + q * 8, dB + t * 4096 + wid * 512);
            }
        }
        const _Float16* ab = &As[cur][0];
        const _Float16* bb = &Bs[cur][0];
#pragma unroll
        for (int ks = 0; ks < 2; ++ks) {
            const int off = ((ks * 4 + lq) ^ xv) * 8;
            half8 a[4], b[2];
#pragma unroll
            for (int i = 0; i < 4; ++i) a[i] = *(const half8*)(ab + (wr + i * 16 + lm) * 64 + off);
#pragma unroll
            for (int j = 0; j < 2; ++j) b[j] = *(const half8*)(bb + (wc + j * 16 + lm) * 64 + off);
#pragma unroll
            for (int i = 0; i < 4; ++i)
#pragma unroll
                for (int j = 0; j < 2; ++j)
                    acc[i][j] = __builtin_amdgcn_mfma_f32_16x16x32_f16(a[i], b[j], acc[i][j], 0, 0, 0);
        }
        __syncthreads();
        cur ^= 1;
    }
#pragma unroll
    for (int j = 0; j < 2; ++j) {
        int n = n0 + wc + j * 16 + lm;
        int net = n >> 8, ncol = n & 255;
        float bi = b1cat[n];
        _Float16* hp = H + (long)net * ((long)M1 * 256) + ncol;
#pragma unroll
        for (int i = 0; i < 4; ++i) {
            int mrow = m0 + wr + i * 16 + lq * 4;
#pragma unroll
            for (int rg = 0; rg < 4; ++rg) {
                float v = acc[i][j][rg] + bi;
                v = v > 0.f ? v : 0.f;
                hp[(long)(mrow + rg) * 256] = (_Float16)v;
            }
        }
    }
}

// ---------------- gemm2: Osum[net][B][512] = sum_o relu(H[net][o] @ W2^T + b2) ----------------
// BM=BN=128, BK=64, 8 waves (64x32), 12 rounds (3 obj x 4 kc)
__global__ __launch_bounds__(512) void gemm_sum(const _Float16* __restrict__ H,
                                                const _Float16* __restrict__ W2t,
                                                const float* __restrict__ b2cat,
                                                _Float16* __restrict__ Osum) {
    __shared__ _Float16 As[2][8192];
    __shared__ _Float16 Bs[2][8192];
    const int tid = threadIdx.x;
    // 4096 blocks = 8 XCD x 512; within XCD: sub = {y(2b), net(1b)}, y fastest -> 4 consecutive share A panel
    int bid = blockIdx.x;
    int w = (bid & 7) * 512 + (bid >> 3);
    const int b0 = (w >> 3) * 128;
    const int sub = w & 7;
    const int n0 = (sub & 3) * 128, net = sub >> 2;
    const _Float16* Ab = H + (long)net * ((long)M1 * 256) + (long)b0 * 256;
    const _Float16* Bb = W2t + (long)net * 131072 + (long)n0 * 256;
    const float* bp = b2cat + net * 512;
    const int wid = tid >> 6, lane = tid & 63;
    const int lm = lane & 15, lq = lane >> 4;
    const int wr = (wid >> 2) * 64, wc = (wid & 3) * 32;
    const int xv = lm & 7;

    float bi[2];
#pragma unroll
    for (int j = 0; j < 2; ++j) bi[j] = bp[n0 + wc + j * 16 + lm];

#pragma unroll
    for (int t = 0; t < 2; ++t) {   // stage round 0 (obj 0, ko 0)
        int c = t * 512 + tid, row = c >> 3, q = (c & 7) ^ (row & 7);
        GLL16(Ab + (long)row * 256 + q * 8, &As[0][0] + t * 4096 + wid * 512);
        GLL16(Bb + (long)row * 256 + q * 8, &Bs[0][0] + t * 4096 + wid * 512);
    }
    __syncthreads();

    f32x4 accA[4][2] = {};
    f32x4 sum[4][2] = {};
    int cur = 0;
    for (int r = 0; r < 12; ++r) {
        if (r < 11) {
            int rn = r + 1;
            int obj = rn >> 2, ko = (rn & 3) * 64;
            _Float16* dA = &As[cur ^ 1][0];
            _Float16* dB = &Bs[cur ^ 1][0];
#pragma unroll
            for (int t = 0; t < 2; ++t) {
                int c = t * 512 + tid, row = c >> 3, q = (c & 7) ^ (row & 7);
                GLL16(Ab + ((long)obj * BATCH + row) * 256 + ko + q * 8, dA + t * 4096 + wid * 512);
                GLL16(Bb + (long)row * 256 + ko + q * 8, dB + t * 4096 + wid * 512);
            }
        }
        const _Float16* ab = &As[cur][0];
        const _Float16* bb = &Bs[cur][0];
#pragma unroll
        for (int ks = 0; ks < 2; ++ks) {
            const int off = ((ks * 4 + lq) ^ xv) * 8;
            half8 a[4], b[2];
#pragma unroll
            for (int i = 0; i < 4; ++i) a[i] = *(const half8*)(ab + (wr + i * 16 + lm) * 64 + off);
#pragma unroll
            for (int j = 0; j < 2; ++j) b[j] = *(const half8*)(bb + (wc + j * 16 + lm) * 64 + off);
#pragma unroll
            for (int i = 0; i < 4; ++i)
#pragma unroll
                for (int j = 0; j < 2; ++j)
                    accA[i][j] = __builtin_amdgcn_mfma_f32_16x16x32_f16(a[i], b[j], accA[i][j], 0, 0, 0);
        }
        if ((r & 3) == 3) {  // object boundary: bias + relu + accumulate, reset
#pragma unroll
            for (int i = 0; i < 4; ++i)
#pragma unroll
                for (int j = 0; j < 2; ++j) {
#pragma unroll
                    for (int rg = 0; rg < 4; ++rg) {
                        float v = accA[i][j][rg] + bi[j];
                        sum[i][j][rg] += (v > 0.f ? v : 0.f);
                    }
                    accA[i][j] = f32x4{0.f, 0.f, 0.f, 0.f};
                }
        }
        __syncthreads();
        cur ^= 1;
    }
    _Float16* op = Osum + (long)net * ((long)BATCH * 512);
#pragma unroll
    for (int j = 0; j < 2; ++j) {
        int n = n0 + wc + j * 16 + lm;
#pragma unroll
        for (int i = 0; i < 4; ++i) {
            int mrow = b0 + wr + i * 16 + lq * 4;
#pragma unroll
            for (int rg = 0; rg < 4; ++rg)
                op[(long)(mrow + rg) * 512 + n] = (_Float16)sum[i][j][rg];
        }
    }
}

// ---------------- gemm3+qdot fused: q = relu(Osum @ R1 + rb1) . w2 + b2 ----------------
// BM=128, BN=256 (full), BK=64, 8 waves (64x64), K=512 -> 8 rounds; per net
__global__ __launch_bounds__(512) void gemm3q(const _Float16* __restrict__ Osum,
                                              const _Float16* __restrict__ R1t,
                                              const float* __restrict__ rbias,
                                              const float* __restrict__ r1w2,
                                              const float* __restrict__ r2w2,
                                              const float* __restrict__ r1b2,
                                              const float* __restrict__ r2b2,
                                              float* __restrict__ out) {
    __shared__ _Float16 As[2][8192];
    __shared__ _Float16 Bs[2][16384];
    __shared__ float qlds[128];
    const int tid = threadIdx.x;
    const int b0 = blockIdx.x * 128, net = blockIdx.z;
    if (tid < 128) qlds[tid] = 0.f;
    const _Float16* Ab = Osum + (long)net * ((long)BATCH * 512) + (long)b0 * 512;
    const _Float16* Bb = R1t + (long)net * 131072;
    const int wid = tid >> 6, lane = tid & 63;
    const int lm = lane & 15, lq = lane >> 4;
    const int wr = (wid >> 2) * 64, wc = (wid & 3) * 64;
    const int xv = lm & 7;

#pragma unroll
    for (int t = 0; t < 2; ++t) {
        int c = t * 512 + tid, row = c >> 3, q = (c & 7) ^ (row & 7);
        GLL16(Ab + (long)row * 512 + q * 8, &As[0][0] + t * 4096 + wid * 512);
    }
#pragma unroll
    for (int t = 0; t < 4; ++t) {
        int c = t * 512 + tid, row = c >> 3, q = (c & 7) ^ (row & 7);
        GLL16(Bb + (long)row * 512 + q * 8, &Bs[0][0] + t * 4096 + wid * 512);
    }
    __syncthreads();

    f32x4 acc[4][4] = {};
    int cur = 0;
    for (int r = 0; r < 8; ++r) {
        if (r < 7) {
            int ko = (r + 1) * 64;
            _Float16* dA = &As[cur ^ 1][0];
            _Float16* dB = &Bs[cur ^ 1][0];
#pragma unroll
            for (int t = 0; t < 2; ++t) {
                int c = t * 512 + tid, row = c >> 3, q = (c & 7) ^ (row & 7);
                GLL16(Ab + (long)row * 512 + ko + q * 8, dA + t * 4096 + wid * 512);
            }
#pragma unroll
            for (int t = 0; t < 4; ++t) {
                int c = t * 512 + tid, row = c >> 3, q = (c & 7) ^ (row & 7);
                GLL16(Bb + (long)row * 512 + ko + q * 8, dB + t * 4096 + wid * 512);
            }
        }
        const _Float16* ab = &As[cur][0];
        const _Float16* bb = &Bs[cur][0];
#pragma unroll
        for (int ks = 0; ks < 2; ++ks) {
            const int off = ((ks * 4 + lq) ^ xv) * 8;
            half8 a[4], b[4];
#pragma unroll
            for (int i = 0; i < 4; ++i) a[i] = *(const half8*)(ab + (wr + i * 16 + lm) * 64 + off);
#pragma unroll
            for (int j = 0; j < 4; ++j) b[j] = *(const half8*)(bb + (wc + j * 16 + lm) * 64 + off);
#pragma unroll
            for (int i = 0; i < 4; ++i)
#pragma unroll
                for (int j = 0; j < 4; ++j)
                    acc[i][j] = __builtin_amdgcn_mfma_f32_16x16x32_f16(a[i], b[j], acc[i][j], 0, 0, 0);
        }
        __syncthreads();
        cur ^= 1;
    }
    // epilogue: relu + dot with w2, reduce
    const float* w2 = net ? r2w2 : r1w2;
    const float* rb = rbias + net * 256;
    float w2v[4], bv[4];
#pragma unroll
    for (int j = 0; j < 4; ++j) {
        int col = wc + j * 16 + lm;
        w2v[j] = w2[col];
        bv[j] = rb[col];
    }
    f32x4 qp[4] = {};
#pragma unroll
    for (int i = 0; i < 4; ++i)
#pragma unroll
        for (int j = 0; j < 4; ++j)
#pragma unroll
            for (int rg = 0; rg < 4; ++rg) {
                float v = acc[i][j][rg] + bv[j];
                v = v > 0.f ? v : 0.f;
                qp[i][rg] += v * w2v[j];
            }
#pragma unroll
    for (int d = 1; d < 16; d <<= 1)
#pragma unroll
        for (int i = 0; i < 4; ++i)
#pragma unroll
            for (int rg = 0; rg < 4; ++rg)
                qp[i][rg] += __shfl_xor(qp[i][rg], d, 64);
    if ((lane & 15) == 0) {
#pragma unroll
        for (int i = 0; i < 4; ++i)
#pragma unroll
            for (int rg = 0; rg < 4; ++rg)
                atomicAdd(&qlds[wr + i * 16 + lq * 4 + rg], qp[i][rg]);
    }
    __syncthreads();
    if (tid < 128)
        out[(long)net * BATCH + b0 + tid] = qlds[tid] + (net ? r2b2[0] : r1b2[0]);
}

extern "C" void kernel_launch(void* const* d_in, const int* in_sizes, int n_in,
                              void* d_out, int out_size, void* d_ws, size_t ws_size,
                              hipStream_t stream) {
    const float* obs  = (const float*)d_in[0];
    const float* act  = (const float*)d_in[1];
    const float* nodes= (const float*)d_in[2];
    const float* p1w1 = (const float*)d_in[3];  const float* p1b1 = (const float*)d_in[4];
    const float* p1w2 = (const float*)d_in[5];  const float* p1b2 = (const float*)d_in[6];
    const float* p2w1 = (const float*)d_in[7];  const float* p2b1 = (const float*)d_in[8];
    const float* p2w2 = (const float*)d_in[9];  const float* p2b2 = (const float*)d_in[10];
    const float* r1w1 = (const float*)d_in[11]; const float* r1b1 = (const float*)d_in[12];
    const float* r1w2 = (const float*)d_in[13]; const float* r1b2 = (const float*)d_in[14];
    const float* r2w1 = (const float*)d_in[15]; const float* r2b1 = (const float*)d_in[16];
    const float* r2w2 = (const float*)d_in[17]; const float* r2b2 = (const float*)d_in[18];

    // workspace layout (bytes, 16B aligned)
    const size_t oW1t  = 0;           // 512*192*2     = 196,608
    const size_t oW2t  = 196608;      // 2*512*256*2   = 524,288
    const size_t oR1t  = 720896;      // 2*256*512*2   = 524,288
    const size_t oB1   = 1245184;     // 512*4
    const size_t oB2   = 1247232;     // 2*512*4
    const size_t oRB   = 1251328;     // 2*256*4
    const size_t oXO   = 1253376;     // max(Xh 75,497,472 ; Osum 134,217,728) aliased in time
    const size_t oH    = 135471104;   // H 201,326,592
    const size_t need  = 336797696;
    if (ws_size < need) return;

    char* ws = (char*)d_ws;
    _Float16* W1t  = (_Float16*)(ws + oW1t);
    _Float16* W2t  = (_Float16*)(ws + oW2t);
    _Float16* R1t  = (_Float16*)(ws + oR1t);
    float*    b1cat= (float*)(ws + oB1);
    float*    b2cat= (float*)(ws + oB2);
    float*    rbias= (float*)(ws + oRB);
    _Float16* Xh   = (_Float16*)(ws + oXO);
    _Float16* Osum = (_Float16*)(ws + oXO);  // alias: Xh dead after gemm1
    _Float16* H    = (_Float16*)(ws + oH);
    float* out = (float*)d_out;

    prep_kernel<<<2440, 256, 0, stream>>>(p1w1, p2w1, p1w2, p2w2, r1w1, r2w1,
                                          p1b1, p2b1, p1b2, p2b2, r1b1, r2b1,
                                          W1t, W2t, R1t, b1cat, b2cat, rbias);
    build_x<<<18432, 256, 0, stream>>>(obs, act, nodes, Xh);
    gemm1<<<6144, 512, 0, stream>>>(Xh, W1t, b1cat, H);
    gemm_sum<<<4096, 512, 0, stream>>>(H, W2t, b2cat, Osum);
    gemm3q<<<dim3(512, 1, 2), 512, 0, stream>>>(Osum, R1t, rbias, r1w2, r2w2, r1b2, r2b2, out);
}